// Round 20
// baseline (123.377 us; speedup 1.0000x reference)
//
#include <hip/hip_runtime.h>
#include <hip/hip_bf16.h>

#define BATCH 16
#define SEQ   2048
#define HD    128
#define QBLK  64
#define KVBLK 32
#define NW    4

typedef __attribute__((ext_vector_type(8))) short bf16x8;
typedef __attribute__((ext_vector_type(4))) float f32x4;
typedef __attribute__((ext_vector_type(4))) short s16x4;

__device__ __forceinline__ short f2bf(float x) {
    __hip_bfloat16 h = __float2bfloat16(x);
    return *reinterpret_cast<short*>(&h);
}

// r18 inner loop EXACTLY (111.3us best: dbuf K+V, 1 barrier/iter, no-max
// softmax, rcp-hoist, setprio, (256,2) -> VGPR~92). Only change: 2-way KV
// split across blocks (grid 512->1024) to break the grid-imposed 2-blocks/CU
// cap (occ 22%). LDS 42KB -> 3 blocks/CU = 12 waves/CU. No-max softmax makes
// the merge trivial: O=(O0+O1)/(l0+l1), no (m,l) coupling.
template<int NTILES, bool PARTIAL>
__global__ __launch_bounds__(256, 2)
void attn_fused(const float* __restrict__ Q, const float* __restrict__ K,
                const float* __restrict__ V, const float* __restrict__ ISF,
                float* __restrict__ O, float* __restrict__ opart,
                float* __restrict__ lsum)
{
    const int tid  = threadIdx.x;
    const int lane = tid & 63;
    const int wv   = tid >> 6;      // wave 0..3, owns q-rows [wv*16, wv*16+16)
    const int lg   = lane >> 4;     // 16-lane group 0..3
    const int lc   = lane & 15;

    const int bidx = blockIdx.x;
    const int qt   = PARTIAL ? (bidx >> 1) : bidx;          // q-tile 0..511
    const int kvb  = PARTIAL ? ((bidx & 1) * (NTILES * KVBLK)) : 0;
    const int b    = qt >> 5;
    const int q0   = (qt & 31) * QBLK;

    __shared__ short Klds[2][32 * 128];    // XOR-swizzled 16B chunks
    __shared__ short Vtlds[2][128 * 40];   // transposed V [d][kv], stride 40 shorts
    __shared__ short Plds[NW * 16 * 40];

    // ---- hoist Q fragments (A operand): row = q0 + wv*16 + lc, k = ks*32 + lg*8 + j ----
    bf16x8 qf[4];
    {
        const float* qrow = Q + ((size_t)b * SEQ + q0 + wv * 16 + lc) * HD;
        #pragma unroll
        for (int ks = 0; ks < 4; ++ks) {
            const float* p = qrow + ks * 32 + lg * 8;
            float4 x0 = *reinterpret_cast<const float4*>(p);
            float4 x1 = *reinterpret_cast<const float4*>(p + 4);
            bf16x8 f;
            f[0]=f2bf(x0.x); f[1]=f2bf(x0.y); f[2]=f2bf(x0.z); f[3]=f2bf(x0.w);
            f[4]=f2bf(x1.x); f[5]=f2bf(x1.y); f[6]=f2bf(x1.z); f[7]=f2bf(x1.w);
            qf[ks] = f;
        }
    }

    f32x4 oacc[8];
    #pragma unroll
    for (int i = 0; i < 8; ++i) oacc[i] = (f32x4){0.f, 0.f, 0.f, 0.f};
    float l_part[4] = {0.f, 0.f, 0.f, 0.f};   // per-lane partial row sums

    const float* kbase = K + (size_t)b * SEQ * HD;
    const float* vbase = V + (size_t)b * SEQ * HD;
    const float* ibase = ISF + ((size_t)b * SEQ + q0 + wv * 16) * SEQ;

    float4 kreg[4];
    float  vreg[4][4];
    float  isf_cur[8], isf_nxt[8];  // isf_cur holds rcp(isf)*log2e

    auto LOAD = [&](int kv0) {
        const float* kb = kbase + (size_t)kv0 * HD;
        const float* vb = vbase + (size_t)kv0 * HD;
        #pragma unroll
        for (int r = 0; r < 4; ++r) {
            int idx = r * 256 + tid;
            kreg[r] = *reinterpret_cast<const float4*>(kb + (size_t)(idx >> 5) * HD + (idx & 31) * 4);
        }
        #pragma unroll
        for (int r = 0; r < 4; ++r) {
            int idx = r * 256 + tid;
            int d = idx & 127, kq = idx >> 7;
            #pragma unroll
            for (int j = 0; j < 4; ++j)
                vreg[r][j] = vb[(size_t)(kq * 4 + j) * HD + d];
        }
    };
    auto LOAD_ISF = [&](int kv0, float* dst) {
        #pragma unroll
        for (int nt = 0; nt < 2; ++nt)
            #pragma unroll
            for (int r = 0; r < 4; ++r)
                dst[nt * 4 + r] = ibase[(size_t)(lg * 4 + r) * SEQ + kv0 + nt * 16 + lc];
    };
    auto STORE = [&](int buf) {
        #pragma unroll
        for (int r = 0; r < 4; ++r) {
            int idx = r * 256 + tid;
            int kvr = idx >> 5, d4 = idx & 31;
            s16x4 s;
            s[0]=f2bf(kreg[r].x); s[1]=f2bf(kreg[r].y); s[2]=f2bf(kreg[r].z); s[3]=f2bf(kreg[r].w);
            int chunk = (d4 >> 1) ^ (kvr & 7);
            *reinterpret_cast<s16x4*>(&Klds[buf][kvr * 128 + chunk * 8 + (d4 & 1) * 4]) = s;
        }
        #pragma unroll
        for (int r = 0; r < 4; ++r) {
            int idx = r * 256 + tid;
            int d = idx & 127, kq = idx >> 7;
            s16x4 s;
            #pragma unroll
            for (int j = 0; j < 4; ++j) s[j] = f2bf(vreg[r][j]);
            *reinterpret_cast<s16x4*>(&Vtlds[buf][d * 40 + kq * 4]) = s;
        }
    };

    // ---- prologue: tile 0 into buf 0 ----
    LOAD(kvb);
    LOAD_ISF(kvb, isf_nxt);
    STORE(0);
    __syncthreads();
    #pragma unroll
    for (int i = 0; i < 8; ++i)
        isf_cur[i] = __builtin_amdgcn_rcpf(isf_nxt[i]) * 1.44269504f;

    int cur = 0;
    for (int t = 0; t < NTILES; ++t) {
        const bool more = (t + 1 < NTILES);
        const int kv0n = kvb + (t + 1) * KVBLK;
        if (more) { LOAD(kv0n); LOAD_ISF(kv0n, isf_nxt); }   // in flight under compute

        // ---- S = Q·K^T (16 rows x 32 cols per wave) ----
        f32x4 sacc[2];
        sacc[0] = (f32x4){0.f,0.f,0.f,0.f};
        sacc[1] = (f32x4){0.f,0.f,0.f,0.f};
        __builtin_amdgcn_s_setprio(1);
        #pragma unroll
        for (int nt = 0; nt < 2; ++nt) {
            int n = lc + nt * 16;
            #pragma unroll
            for (int ks = 0; ks < 4; ++ks) {
                int chunk = (ks * 4 + lg) ^ (n & 7);
                bf16x8 bf = *reinterpret_cast<const bf16x8*>(&Klds[cur][n * 128 + chunk * 8]);
                sacc[nt] = __builtin_amdgcn_mfma_f32_16x16x32_bf16(qf[ks], bf, sacc[nt], 0, 0, 0);
            }
        }
        __builtin_amdgcn_s_setprio(0);

        // ---- P = exp2(qk * rcp(isf)*log2e), unnormalized (|score| <= ~9) ----
        short pb[2][4];
        #pragma unroll
        for (int nt = 0; nt < 2; ++nt)
            #pragma unroll
            for (int r = 0; r < 4; ++r) {
                float p = __builtin_amdgcn_exp2f(sacc[nt][r] * isf_cur[nt * 4 + r]);
                l_part[r] += p;
                pb[nt][r] = f2bf(p);
            }

        // ---- P: D-layout -> A-frag layout via per-wave LDS tile ----
        short* pw = &Plds[wv * 16 * 40];
        #pragma unroll
        for (int nt = 0; nt < 2; ++nt)
            #pragma unroll
            for (int r = 0; r < 4; ++r)
                pw[(lg * 4 + r) * 40 + nt * 16 + lc] = pb[nt][r];
        bf16x8 pa = *reinterpret_cast<const bf16x8*>(&pw[lc * 40 + lg * 8]);

        // ---- O += P·V ----
        __builtin_amdgcn_s_setprio(1);
        #pragma unroll
        for (int dt = 0; dt < 8; ++dt) {
            bf16x8 vf = *reinterpret_cast<const bf16x8*>(&Vtlds[cur][(lc + dt * 16) * 40 + lg * 8]);
            oacc[dt] = __builtin_amdgcn_mfma_f32_16x16x32_bf16(pa, vf, oacc[dt], 0, 0, 0);
        }
        __builtin_amdgcn_s_setprio(0);

        // ---- land tile t+1 in the other buffer; single barrier per iter ----
        if (more) STORE(cur ^ 1);
        __syncthreads();
        cur ^= 1;
        #pragma unroll
        for (int i = 0; i < 8; ++i)
            isf_cur[i] = __builtin_amdgcn_rcpf(isf_nxt[i]) * 1.44269504f;
    }

    // ---- epilogue: one-time row-sum reduce (16-lane butterfly) ----
    #pragma unroll
    for (int msk = 1; msk < 16; msk <<= 1)
        #pragma unroll
        for (int r = 0; r < 4; ++r)
            l_part[r] += __shfl_xor(l_part[r], msk, 64);

    if (PARTIAL) {
        // unnormalized O + row sum l to workspace
        const size_t rowbase = (size_t)bidx * 64 + wv * 16;
        #pragma unroll
        for (int r = 0; r < 4; ++r) {
            float* orow = opart + (rowbase + lg * 4 + r) * HD;
            #pragma unroll
            for (int dt = 0; dt < 8; ++dt)
                orow[lc + dt * 16] = oacc[dt][r];
            if (lc == 0) lsum[rowbase + lg * 4 + r] = l_part[r];
        }
    } else {
        float* ob = O + ((size_t)b * SEQ + q0 + wv * 16) * HD;
        #pragma unroll
        for (int r = 0; r < 4; ++r) {
            float inv_l = 1.0f / l_part[r];
            float* orow = ob + (size_t)(lg * 4 + r) * HD;
            #pragma unroll
            for (int dt = 0; dt < 8; ++dt)
                orow[lc + dt * 16] = oacc[dt][r] * inv_l;
        }
    }
}

// merge: O = (O0 + O1) / (l0 + l1)   (no-max softmax -> no max coupling)
__global__ __launch_bounds__(256)
void merge_k(const float* __restrict__ opart, const float* __restrict__ lsum,
             float* __restrict__ O)
{
    int gid = blockIdx.x * 256 + threadIdx.x;   // 1,048,576 threads
    int row = gid >> 5;                         // global q-row 0..32767
    int c4  = gid & 31;                         // float4 column
    int qt  = row >> 6;
    int rin = row & 63;
    size_t i0 = (size_t)(2 * qt) * 64 + rin;    // half 0 row
    size_t i1 = i0 + 64;                        // half 1 row
    float inv = 1.0f / (lsum[i0] + lsum[i1]);
    float4 o0 = reinterpret_cast<const float4*>(opart)[i0 * 32 + c4];
    float4 o1 = reinterpret_cast<const float4*>(opart)[i1 * 32 + c4];
    float4 out;
    out.x = (o0.x + o1.x) * inv;
    out.y = (o0.y + o1.y) * inv;
    out.z = (o0.z + o1.z) * inv;
    out.w = (o0.w + o1.w) * inv;
    reinterpret_cast<float4*>(O)[(size_t)row * 32 + c4] = out;
}

extern "C" void kernel_launch(void* const* d_in, const int* in_sizes, int n_in,
                              void* d_out, int out_size, void* d_ws, size_t ws_size,
                              hipStream_t stream) {
    const float* q   = (const float*)d_in[0];
    const float* k   = (const float*)d_in[1];
    const float* v   = (const float*)d_in[2];
    const float* isf = (const float*)d_in[3];
    float* out = (float*)d_out;

    const size_t opart_elems = (size_t)1024 * 64 * HD;       // 8,388,608 floats
    const size_t lsum_elems  = (size_t)1024 * 64;            // 65,536 floats
    const size_t need = (opart_elems + lsum_elems) * sizeof(float);  // 33.8 MB
    if (ws_size >= need) {
        float* opart = (float*)d_ws;
        float* lsum  = opart + opart_elems;
        attn_fused<32, true><<<dim3(1024), 256, 0, stream>>>(q, k, v, isf, out, opart, lsum);
        merge_k<<<dim3(4096), 256, 0, stream>>>(opart, lsum, out);
    } else {
        attn_fused<64, false><<<dim3(512), 256, 0, stream>>>(q, k, v, isf, out, out, out);
    }
}

// Round 21
// 115.821 us; speedup vs baseline: 1.0652x; 1.0652x over previous
//
#include <hip/hip_runtime.h>
#include <hip/hip_bf16.h>

#define BATCH 16
#define SEQ   2048
#define HD    128
#define QBLK  64
#define KVBLK 32
#define NT    (SEQ / KVBLK)
#define NW    4

typedef __attribute__((ext_vector_type(8))) short bf16x8;
typedef __attribute__((ext_vector_type(4))) float f32x4;
typedef __attribute__((ext_vector_type(4))) short s16x4;

__device__ __forceinline__ short f2bf(float x) {
    __hip_bfloat16 h = __float2bfloat16(x);
    return *reinterpret_cast<short*>(&h);
}

// r18 (111.3us best) + 2-deep prefetch with counted-wait barriers.
// __syncthreads compiles to s_waitcnt vmcnt(0) lgkmcnt(0) + s_barrier -> every
// prefetch must land within ONE compute phase (the m97 barrier-drain stall).
// Replace with lgkmcnt(0)-only + raw s_barrier (LDS hazards fully covered:
// cross-wave hazard is only ds_writes) and prefetch TWO tiles ahead in
// A/B register sets -> load window = 2 compute phases >> HBM latency.
__device__ __forceinline__ void bar_lgkm() {
    asm volatile("s_waitcnt lgkmcnt(0)" ::: "memory");
    __builtin_amdgcn_s_barrier();
}

__global__ __launch_bounds__(256, 2)
void attn_fused(const float* __restrict__ Q, const float* __restrict__ K,
                const float* __restrict__ V, const float* __restrict__ ISF,
                float* __restrict__ O)
{
    const int tid  = threadIdx.x;
    const int lane = tid & 63;
    const int wv   = tid >> 6;      // wave 0..3, owns q-rows [wv*16, wv*16+16)
    const int lg   = lane >> 4;     // 16-lane group 0..3
    const int lc   = lane & 15;

    const int bidx = blockIdx.x;
    const int b    = bidx >> 5;            // 32 q-tiles per batch
    const int q0   = (bidx & 31) * QBLK;

    __shared__ short Klds[2][32 * 128];    // XOR-swizzled 16B chunks
    __shared__ short Vtlds[2][128 * 40];   // transposed V [d][kv], stride 40 shorts
    __shared__ short Plds[NW * 16 * 40];

    // ---- hoist Q fragments (A operand): row = q0 + wv*16 + lc, k = ks*32 + lg*8 + j ----
    bf16x8 qf[4];
    {
        const float* qrow = Q + ((size_t)b * SEQ + q0 + wv * 16 + lc) * HD;
        #pragma unroll
        for (int ks = 0; ks < 4; ++ks) {
            const float* p = qrow + ks * 32 + lg * 8;
            float4 x0 = *reinterpret_cast<const float4*>(p);
            float4 x1 = *reinterpret_cast<const float4*>(p + 4);
            bf16x8 f;
            f[0]=f2bf(x0.x); f[1]=f2bf(x0.y); f[2]=f2bf(x0.z); f[3]=f2bf(x0.w);
            f[4]=f2bf(x1.x); f[5]=f2bf(x1.y); f[6]=f2bf(x1.z); f[7]=f2bf(x1.w);
            qf[ks] = f;
        }
    }

    f32x4 oacc[8];
    #pragma unroll
    for (int i = 0; i < 8; ++i) oacc[i] = (f32x4){0.f, 0.f, 0.f, 0.f};
    float l_part[4] = {0.f, 0.f, 0.f, 0.f};   // per-lane partial row sums

    const float* kbase = K + (size_t)b * SEQ * HD;
    const float* vbase = V + (size_t)b * SEQ * HD;
    const float* ibase = ISF + ((size_t)b * SEQ + q0 + wv * 16) * SEQ;

    // two independent prefetch register sets (static names, rule #20)
    float4 kregA[4], kregB[4];
    float  vregA[4][4], vregB[4][4];
    float  isfA[8], isfB[8];
    float  isf_cur[8];              // rcp(isf)*log2e for the tile being computed

    #define LOADSET(SET, kv0)                                                        \
        {                                                                            \
            const float* kb_ = kbase + (size_t)(kv0) * HD;                           \
            const float* vb_ = vbase + (size_t)(kv0) * HD;                           \
            _Pragma("unroll")                                                        \
            for (int r = 0; r < 4; ++r) {                                            \
                int idx = r * 256 + tid;                                             \
                kreg##SET[r] = *reinterpret_cast<const float4*>(                     \
                    kb_ + (size_t)(idx >> 5) * HD + (idx & 31) * 4);                 \
            }                                                                        \
            _Pragma("unroll")                                                        \
            for (int r = 0; r < 4; ++r) {                                            \
                int idx = r * 256 + tid;                                             \
                int d_ = idx & 127, kq_ = idx >> 7;                                  \
                _Pragma("unroll")                                                    \
                for (int j = 0; j < 4; ++j)                                          \
                    vreg##SET[r][j] = vb_[(size_t)(kq_ * 4 + j) * HD + d_];          \
            }                                                                        \
            _Pragma("unroll")                                                        \
            for (int nt = 0; nt < 2; ++nt)                                           \
                _Pragma("unroll")                                                    \
                for (int r = 0; r < 4; ++r)                                          \
                    isf##SET[nt * 4 + r] =                                           \
                        ibase[(size_t)(lg * 4 + r) * SEQ + (kv0) + nt * 16 + lc];    \
        }

    #define STORESET(SET, buf)                                                       \
        {                                                                            \
            _Pragma("unroll")                                                        \
            for (int r = 0; r < 4; ++r) {                                            \
                int idx = r * 256 + tid;                                             \
                int kvr = idx >> 5, d4 = idx & 31;                                   \
                s16x4 s_;                                                            \
                s_[0]=f2bf(kreg##SET[r].x); s_[1]=f2bf(kreg##SET[r].y);              \
                s_[2]=f2bf(kreg##SET[r].z); s_[3]=f2bf(kreg##SET[r].w);              \
                int chunk = (d4 >> 1) ^ (kvr & 7);                                   \
                *reinterpret_cast<s16x4*>(                                           \
                    &Klds[buf][kvr * 128 + chunk * 8 + (d4 & 1) * 4]) = s_;          \
            }                                                                        \
            _Pragma("unroll")                                                        \
            for (int r = 0; r < 4; ++r) {                                            \
                int idx = r * 256 + tid;                                             \
                int d_ = idx & 127, kq_ = idx >> 7;                                  \
                s16x4 s_;                                                            \
                _Pragma("unroll")                                                    \
                for (int j = 0; j < 4; ++j) s_[j] = f2bf(vreg##SET[r][j]);           \
                *reinterpret_cast<s16x4*>(&Vtlds[buf][d_ * 40 + kq_ * 4]) = s_;      \
            }                                                                        \
        }

    #define SETISF(SET)                                                              \
        _Pragma("unroll")                                                            \
        for (int i = 0; i < 8; ++i)                                                  \
            isf_cur[i] = __builtin_amdgcn_rcpf(isf##SET[i]) * 1.44269504f;

    #define COMPUTE(buf)                                                             \
        {                                                                            \
            f32x4 sacc[2];                                                           \
            sacc[0] = (f32x4){0.f,0.f,0.f,0.f};                                      \
            sacc[1] = (f32x4){0.f,0.f,0.f,0.f};                                      \
            __builtin_amdgcn_s_setprio(1);                                           \
            _Pragma("unroll")                                                        \
            for (int nt = 0; nt < 2; ++nt) {                                         \
                int n_ = lc + nt * 16;                                               \
                _Pragma("unroll")                                                    \
                for (int ks = 0; ks < 4; ++ks) {                                     \
                    int chunk = (ks * 4 + lg) ^ (n_ & 7);                            \
                    bf16x8 bf_ = *reinterpret_cast<const bf16x8*>(                   \
                        &Klds[buf][n_ * 128 + chunk * 8]);                           \
                    sacc[nt] = __builtin_amdgcn_mfma_f32_16x16x32_bf16(              \
                        qf[ks], bf_, sacc[nt], 0, 0, 0);                             \
                }                                                                    \
            }                                                                        \
            __builtin_amdgcn_s_setprio(0);                                           \
            short pb[2][4];                                                          \
            _Pragma("unroll")                                                        \
            for (int nt = 0; nt < 2; ++nt)                                           \
                _Pragma("unroll")                                                    \
                for (int r = 0; r < 4; ++r) {                                        \
                    float p_ = __builtin_amdgcn_exp2f(                               \
                        sacc[nt][r] * isf_cur[nt * 4 + r]);                          \
                    l_part[r] += p_;                                                 \
                    pb[nt][r] = f2bf(p_);                                            \
                }                                                                    \
            short* pw = &Plds[wv * 16 * 40];                                         \
            _Pragma("unroll")                                                        \
            for (int nt = 0; nt < 2; ++nt)                                           \
                _Pragma("unroll")                                                    \
                for (int r = 0; r < 4; ++r)                                          \
                    pw[(lg * 4 + r) * 40 + nt * 16 + lc] = pb[nt][r];                \
            bf16x8 pa = *reinterpret_cast<const bf16x8*>(&pw[lc * 40 + lg * 8]);     \
            __builtin_amdgcn_s_setprio(1);                                           \
            _Pragma("unroll")                                                        \
            for (int dt = 0; dt < 8; ++dt) {                                         \
                bf16x8 vf = *reinterpret_cast<const bf16x8*>(                        \
                    &Vtlds[buf][(lc + dt * 16) * 40 + lg * 8]);                      \
                oacc[dt] = __builtin_amdgcn_mfma_f32_16x16x32_bf16(                  \
                    pa, vf, oacc[dt], 0, 0, 0);                                      \
            }                                                                        \
            __builtin_amdgcn_s_setprio(0);                                           \
        }

    // ---- prologue: tile 0 staged, tile 1 in flight ----
    LOADSET(A, 0);
    STORESET(A, 0);
    LOADSET(B, KVBLK);
    bar_lgkm();
    SETISF(A);

    // ---- main loop: 2 tiles per pass; loads issued 2 tiles ahead ----
    for (int t = 0; t < NT; t += 2) {
        const bool haveA2 = (t + 2 < NT);    // tile t+2 -> A regs
        const bool haveB3 = (t + 3 < NT);    // tile t+3 -> B regs

        if (haveA2) LOADSET(A, (t + 2) * KVBLK);
        COMPUTE(0);                          // tile t from buf0 (isf_cur = A)
        STORESET(B, 1);                      // tile t+1 -> buf1 (B loaded 2 phases ago)
        bar_lgkm();
        SETISF(B);

        if (haveB3) LOADSET(B, (t + 3) * KVBLK);
        COMPUTE(1);                          // tile t+1 from buf1 (isf_cur = B)
        if (haveA2) STORESET(A, 0);          // tile t+2 -> buf0
        bar_lgkm();
        if (haveA2) SETISF(A);
    }

    // ---- epilogue: one-time row-sum reduce (16-lane butterfly), normalize, store ----
    #pragma unroll
    for (int msk = 1; msk < 16; msk <<= 1)
        #pragma unroll
        for (int r = 0; r < 4; ++r)
            l_part[r] += __shfl_xor(l_part[r], msk, 64);

    float* ob = O + ((size_t)b * SEQ + q0 + wv * 16) * HD;
    #pragma unroll
    for (int r = 0; r < 4; ++r) {
        float inv_l = 1.0f / l_part[r];
        float* orow = ob + (size_t)(lg * 4 + r) * HD;
        #pragma unroll
        for (int dt = 0; dt < 8; ++dt)
            orow[lc + dt * 16] = oacc[dt][r] * inv_l;
    }
}

extern "C" void kernel_launch(void* const* d_in, const int* in_sizes, int n_in,
                              void* d_out, int out_size, void* d_ws, size_t ws_size,
                              hipStream_t stream) {
    const float* q   = (const float*)d_in[0];
    const float* k   = (const float*)d_in[1];
    const float* v   = (const float*)d_in[2];
    const float* isf = (const float*)d_in[3];
    float* out = (float*)d_out;
    dim3 grid(BATCH * (SEQ / QBLK));   // 512 blocks
    attn_fused<<<grid, 256, 0, stream>>>(q, k, v, isf, out);
}